// Round 14
// baseline (493.734 us; speedup 1.0000x reference)
//
#include <hip/hip_runtime.h>

// out[b,o] = sum_h W2[o,h]*leaky(h) + b2[o],  h = W1[o]·x[b] + b1[o]
// leaky(t) = 0.6t + 0.4|t|
//   out[b,o] = 0.6(v[o]·x[b]) + c0[o] + sum_h (0.4 W2[o,h])|h|
// R15: stage1 = mfma_f32_16x16x16f16 (K=16 exact, b1 rides f32-C; layouts
// verified R8/R9). stage2 = 4 v_fma_f32 with FREE abs modifier per (ct,tile)
// — deletes the broadcast-B stage2 MFMAs (16x wasted N-columns; half of
// R13's MFMA FLOPs). Linear part = f32 VALU folded into nl's init (exact).
// W1 frags hoisted to 64 VGPR (budget ~114 <=128 — no R14-style spills).
// One fused kernel, 512 blocks x 512 thr (2 blk/CU), reduce = 2 shfl_xor.

#define H_DIM 512

typedef _Float16 f16x4 __attribute__((ext_vector_type(4)));
typedef __fp16   h16x2 __attribute__((ext_vector_type(2)));   // cvt_pkrtz native
typedef float    f32x4 __attribute__((ext_vector_type(4)));
typedef int      i32x2 __attribute__((ext_vector_type(2)));

// o = blk&15, grp = blk>>4 (32). Wave w: 8 tiles, tile0 = grp*64 + w*8.
__global__ __launch_bounds__(512, 4) void mlp_fused(
    const float* __restrict__ x, const float* __restrict__ W1,
    const float* __restrict__ b1, const float* __restrict__ W2,
    const float* __restrict__ b2, float* __restrict__ out) {
    __shared__ f16x4 sm_a1[2048];     // [ct][lane] W1 frags      16 KiB
    __shared__ f32x4 sm_w2c[128];     // [ct][kg] 0.4*W2           2 KiB
    __shared__ f32x4 sm_b1c[128];     // [ct][kg] b1               2 KiB
    __shared__ float red[512];
    __shared__ float v_sm[16];
    __shared__ float c_sm;

    const int tid = threadIdx.x;
    const int o   = blockIdx.x & 15;
    const int grp = blockIdx.x >> 4;
    const float* W1o = W1 + (size_t)o * H_DIM * 16;
    const float* W2o = W2 + (size_t)o * H_DIM;
    const float* b1o = b1 + (size_t)o * H_DIM;

    // ---- phase A: stage fragments ----
#pragma unroll
    for (int i = 0; i < 4; ++i) {
        const int e = tid + 512 * i;          // 0..2047 = [ct][lane]
        const int l = e & 63, ct = e >> 6;
        const int row = l & 15, kg = l >> 4;
        const f32x4 wv = *reinterpret_cast<const f32x4*>(
            W1o + (size_t)(ct * 16 + row) * 16 + kg * 4);
        h16x2 q0 = __builtin_amdgcn_cvt_pkrtz(wv[0], wv[1]);
        h16x2 q1 = __builtin_amdgcn_cvt_pkrtz(wv[2], wv[3]);
        i32x2 vi; vi[0] = __builtin_bit_cast(int, q0); vi[1] = __builtin_bit_cast(int, q1);
        sm_a1[e] = __builtin_bit_cast(f16x4, vi);
    }
    if (tid < 128) {                          // [ct][kg]
        const int kg = tid & 3, ct = tid >> 2;
        f32x4 wv, bv;
#pragma unroll
        for (int r = 0; r < 4; ++r) {
            wv[r] = 0.4f * W2o[ct * 16 + kg * 4 + r];
            bv[r] = b1o[ct * 16 + kg * 4 + r];
        }
        sm_w2c[tid] = wv;
        sm_b1c[tid] = bv;
    }
    {   // v[i] = 0.6 sum_h W2[h] W1[h,i]
        const int i = tid & 15, hc = tid >> 4;     // 32 chunks x 16 h
        float a = 0.f;
#pragma unroll
        for (int hh = 0; hh < 16; ++hh) {
            const int h = hc * 16 + hh;
            a = fmaf(W2o[h], W1o[(size_t)h * 16 + i], a);
        }
        red[tid] = a;
    }
    __syncthreads();
    if (tid < 16) {
        float s = 0.f;
#pragma unroll
        for (int k = 0; k < 32; ++k) s += red[tid + 16 * k];
        v_sm[tid] = 0.6f * s;
    }
    const float cp = W2o[tid] * b1o[tid];
    __syncthreads();
    red[tid] = cp;
    __syncthreads();
    if (tid < 64) {
        float s = 0.f;
#pragma unroll
        for (int k = 0; k < 8; ++k) s += red[tid + 64 * k];
#pragma unroll
        for (int m = 1; m <= 32; m <<= 1) s += __shfl_xor(s, m, 64);
        if (tid == 0) c_sm = 0.6f * s + b2[o];
    }
    __syncthreads();

    // ---- phase B ----
    const int lane = tid & 63, w = tid >> 6;
    const int col = lane & 15, kg = lane >> 4;
    const int tile0 = grp * 64 + w * 8;

    // hoist W1 fragments: 32 x f16x4 = 64 VGPR
    f16x4 A1r[32];
#pragma unroll
    for (int ct = 0; ct < 32; ++ct) A1r[ct] = sm_a1[ct * 64 + lane];
    const f32x4 vr = *reinterpret_cast<const f32x4*>(&v_sm[kg * 4]);
    const float c0 = c_sm;

    // x load + lin init (exact f32) + f16 fold
    f16x4 xf[8];
    float nl[8];
#pragma unroll
    for (int j = 0; j < 8; ++j) {
        const f32x4 xv = *reinterpret_cast<const f32x4*>(
            x + (size_t)((tile0 + j) * 16 + col) * 16 + kg * 4);
        float lp = xv[0] * vr[0];
        lp = fmaf(xv[1], vr[1], lp);
        lp = fmaf(xv[2], vr[2], lp);
        lp = fmaf(xv[3], vr[3], lp);
        nl[j] = lp;
        h16x2 q0 = __builtin_amdgcn_cvt_pkrtz(xv[0], xv[1]);
        h16x2 q1 = __builtin_amdgcn_cvt_pkrtz(xv[2], xv[3]);
        i32x2 xi; xi[0] = __builtin_bit_cast(int, q0); xi[1] = __builtin_bit_cast(int, q1);
        xf[j] = __builtin_bit_cast(f16x4, xi);
    }

#pragma unroll
    for (int ct = 0; ct < 32; ++ct) {
        const f32x4 wv = sm_w2c[ct * 4 + kg];   // broadcast (kg-only addr)
        const f32x4 bv = sm_b1c[ct * 4 + kg];
#pragma unroll
        for (int j = 0; j < 8; ++j) {
            // stage1: d[r] = h[ct*16 + kg*4 + r] for b=col (bias via C)
            const f32x4 d = __builtin_amdgcn_mfma_f32_16x16x16f16(A1r[ct], xf[j], bv, 0, 0, 0);
            // stage2: 4 FMAs, |d| is a free VOP3 source modifier
            nl[j] = fmaf(wv[0], fabsf(d[0]), nl[j]);
            nl[j] = fmaf(wv[1], fabsf(d[1]), nl[j]);
            nl[j] = fmaf(wv[2], fabsf(d[2]), nl[j]);
            nl[j] = fmaf(wv[3], fabsf(d[3]), nl[j]);
        }
    }

    // reduce over kg (lanes differing in bits 4-5) and store
#pragma unroll
    for (int j = 0; j < 8; ++j) {
        float s = nl[j];
        s += __shfl_xor(s, 16, 64);
        s += __shfl_xor(s, 32, 64);
        if (lane < 16)
            out[(size_t)((tile0 + j) * 16 + lane) * 16 + o] = s + c0;
    }
}

extern "C" void kernel_launch(void* const* d_in, const int* in_sizes, int n_in,
                              void* d_out, int out_size, void* d_ws, size_t ws_size,
                              hipStream_t stream) {
    const float* x  = (const float*)d_in[0];
    const float* W1 = (const float*)d_in[1];
    const float* b1 = (const float*)d_in[2];
    const float* W2 = (const float*)d_in[3];
    const float* b2 = (const float*)d_in[4];
    float* out = (float*)d_out;

    mlp_fused<<<512, 512, 0, stream>>>(x, W1, b1, W2, b2, out);
}

// Round 15
// 44.108 us; speedup vs baseline: 11.1936x; 11.1936x over previous
//
#include <hip/hip_runtime.h>

// out[b,o] = sum_h W2[o,h]*leaky(h) + b2[o],  h = W1[o]·x[b] + b1[o]
// leaky(t) = 0.6t + 0.4|t|
//   out[b,o] = 0.6(v[o]·x[b]) + c0[o] + sum_h (0.4 W2[o,h])|h|
// R16 = R15 algorithm (stage1 mfma16 K=16 exact w/ b1-as-C; stage2 = 4
// v_fma_f32 with free |.| modifier; exact-f32 linear init) with the VGPR cap
// FIXED: __launch_bounds__ 2nd arg empirically acts as blocks/CU (R15: (512,4)
// -> VGPR capped 64 -> 1GB scratch spills, 494us; R13: (512,2) -> cap 128).
// (512,2) gives cap 128 vs ~110 needed -> no spill. unroll-2 on ct-loop
// prevents LDS-read hoisting blowup (R14 failure mode).

#define H_DIM 512

typedef _Float16 f16x4 __attribute__((ext_vector_type(4)));
typedef __fp16   h16x2 __attribute__((ext_vector_type(2)));   // cvt_pkrtz native
typedef float    f32x4 __attribute__((ext_vector_type(4)));
typedef int      i32x2 __attribute__((ext_vector_type(2)));

// 512 blocks x 512 thr (8 waves), 2 blocks/CU. o = blk&15, grp = blk>>4 (32).
// Wave w: 8 tiles of 16 batch rows, tile0 = grp*64 + w*8.
__global__ __launch_bounds__(512, 2) void mlp_fused(
    const float* __restrict__ x, const float* __restrict__ W1,
    const float* __restrict__ b1, const float* __restrict__ W2,
    const float* __restrict__ b2, float* __restrict__ out) {
    __shared__ f16x4 sm_a1[2048];     // [ct][lane] W1 frags      16 KiB
    __shared__ f32x4 sm_w2c[128];     // [ct][kg] 0.4*W2           2 KiB
    __shared__ f32x4 sm_b1c[128];     // [ct][kg] b1               2 KiB
    __shared__ float red[512];
    __shared__ float v_sm[16];
    __shared__ float c_sm;

    const int tid = threadIdx.x;
    const int o   = blockIdx.x & 15;
    const int grp = blockIdx.x >> 4;
    const float* W1o = W1 + (size_t)o * H_DIM * 16;
    const float* W2o = W2 + (size_t)o * H_DIM;
    const float* b1o = b1 + (size_t)o * H_DIM;

    // ---- phase A: stage fragments ----
#pragma unroll
    for (int i = 0; i < 4; ++i) {
        const int e = tid + 512 * i;          // 0..2047 = [ct][lane]
        const int l = e & 63, ct = e >> 6;
        const int row = l & 15, kg = l >> 4;
        const f32x4 wv = *reinterpret_cast<const f32x4*>(
            W1o + (size_t)(ct * 16 + row) * 16 + kg * 4);
        h16x2 q0 = __builtin_amdgcn_cvt_pkrtz(wv[0], wv[1]);
        h16x2 q1 = __builtin_amdgcn_cvt_pkrtz(wv[2], wv[3]);
        i32x2 vi; vi[0] = __builtin_bit_cast(int, q0); vi[1] = __builtin_bit_cast(int, q1);
        sm_a1[e] = __builtin_bit_cast(f16x4, vi);
    }
    if (tid < 128) {                          // [ct][kg]
        const int kg = tid & 3, ct = tid >> 2;
        f32x4 wv, bv;
#pragma unroll
        for (int r = 0; r < 4; ++r) {
            wv[r] = 0.4f * W2o[ct * 16 + kg * 4 + r];
            bv[r] = b1o[ct * 16 + kg * 4 + r];
        }
        sm_w2c[tid] = wv;
        sm_b1c[tid] = bv;
    }
    {   // v[i] = 0.6 sum_h W2[h] W1[h,i]
        const int i = tid & 15, hc = tid >> 4;     // 32 chunks x 16 h
        float a = 0.f;
#pragma unroll
        for (int hh = 0; hh < 16; ++hh) {
            const int h = hc * 16 + hh;
            a = fmaf(W2o[h], W1o[(size_t)h * 16 + i], a);
        }
        red[tid] = a;
    }
    __syncthreads();
    if (tid < 16) {
        float s = 0.f;
#pragma unroll
        for (int k = 0; k < 32; ++k) s += red[tid + 16 * k];
        v_sm[tid] = 0.6f * s;
    }
    const float cp = W2o[tid] * b1o[tid];
    __syncthreads();
    red[tid] = cp;
    __syncthreads();
    if (tid < 64) {
        float s = 0.f;
#pragma unroll
        for (int k = 0; k < 8; ++k) s += red[tid + 64 * k];
#pragma unroll
        for (int m = 1; m <= 32; m <<= 1) s += __shfl_xor(s, m, 64);
        if (tid == 0) c_sm = 0.6f * s + b2[o];
    }
    __syncthreads();

    // ---- phase B ----
    const int lane = tid & 63, w = tid >> 6;
    const int col = lane & 15, kg = lane >> 4;
    const int tile0 = grp * 64 + w * 8;

    // hoist W1 fragments: 32 x f16x4 = 64 VGPR (persistent)
    f16x4 A1r[32];
#pragma unroll
    for (int ct = 0; ct < 32; ++ct) A1r[ct] = sm_a1[ct * 64 + lane];
    const f32x4 vr = *reinterpret_cast<const f32x4*>(&v_sm[kg * 4]);
    const float c0 = c_sm;

    // x load + exact-f32 linear init + f16 fold
    f16x4 xf[8];
    float nl[8];
#pragma unroll
    for (int j = 0; j < 8; ++j) {
        const f32x4 xv = *reinterpret_cast<const f32x4*>(
            x + (size_t)((tile0 + j) * 16 + col) * 16 + kg * 4);
        float lp = xv[0] * vr[0];
        lp = fmaf(xv[1], vr[1], lp);
        lp = fmaf(xv[2], vr[2], lp);
        lp = fmaf(xv[3], vr[3], lp);
        nl[j] = lp;
        h16x2 q0 = __builtin_amdgcn_cvt_pkrtz(xv[0], xv[1]);
        h16x2 q1 = __builtin_amdgcn_cvt_pkrtz(xv[2], xv[3]);
        i32x2 xi; xi[0] = __builtin_bit_cast(int, q0); xi[1] = __builtin_bit_cast(int, q1);
        xf[j] = __builtin_bit_cast(f16x4, xi);
    }

#pragma unroll 2
    for (int ct = 0; ct < 32; ++ct) {
        const f32x4 wv = sm_w2c[ct * 4 + kg];   // broadcast (kg-only addr)
        const f32x4 bv = sm_b1c[ct * 4 + kg];
#pragma unroll
        for (int j = 0; j < 8; ++j) {
            // stage1: d[r] = h[ct*16 + kg*4 + r] for b=col (bias via C)
            const f32x4 d = __builtin_amdgcn_mfma_f32_16x16x16f16(A1r[ct], xf[j], bv, 0, 0, 0);
            // stage2: 4 FMAs, |d| is a free VOP3 source modifier
            nl[j] = fmaf(wv[0], fabsf(d[0]), nl[j]);
            nl[j] = fmaf(wv[1], fabsf(d[1]), nl[j]);
            nl[j] = fmaf(wv[2], fabsf(d[2]), nl[j]);
            nl[j] = fmaf(wv[3], fabsf(d[3]), nl[j]);
        }
    }

    // reduce over kg (lanes differing in bits 4-5) and store
#pragma unroll
    for (int j = 0; j < 8; ++j) {
        float s = nl[j];
        s += __shfl_xor(s, 16, 64);
        s += __shfl_xor(s, 32, 64);
        if (lane < 16)
            out[(size_t)((tile0 + j) * 16 + lane) * 16 + o] = s + c0;
    }
}

extern "C" void kernel_launch(void* const* d_in, const int* in_sizes, int n_in,
                              void* d_out, int out_size, void* d_ws, size_t ws_size,
                              hipStream_t stream) {
    const float* x  = (const float*)d_in[0];
    const float* W1 = (const float*)d_in[1];
    const float* b1 = (const float*)d_in[2];
    const float* W2 = (const float*)d_in[3];
    const float* b2 = (const float*)d_in[4];
    float* out = (float*)d_out;

    mlp_fused<<<512, 512, 0, stream>>>(x, W1, b1, W2, b2, out);
}

// Round 16
// 32.851 us; speedup vs baseline: 15.0295x; 1.3427x over previous
//
#include <hip/hip_runtime.h>

// out[b,o] = sum_h W2[o,h]*leaky(h) + b2[o],  h = W1[o]·x[b] + b1[o]
// leaky(t) = 0.6t + 0.4|t|
//   out[b,o] = 0.6(v[o]·x[b]) + c0[o] + sum_h (0.4 W2[o,h])|h|
// R17 = R15 algorithm (stage1 mfma16 K=16 exact, b1 rides f32-C; stage2 = 4
// v_fma_f32 w/ free |.| modifier; exact-f32 linear init), spill-proofed:
// NO register array for W1 frags — read from LDS per ct (runtime LDS index is
// legal; R16's unroll-2 + A1r[ct] register array hit rule #20 -> 82MB scratch,
// VGPR_Count 36). Budget now ~70 VGPR << 128 cap at (512,2) [2nd arg acts as
// blocks/CU: R13=128cap, R15 (512,4)=64cap — both counter-verified].

#define H_DIM 512

typedef _Float16 f16x4 __attribute__((ext_vector_type(4)));
typedef __fp16   h16x2 __attribute__((ext_vector_type(2)));   // cvt_pkrtz native
typedef float    f32x4 __attribute__((ext_vector_type(4)));
typedef int      i32x2 __attribute__((ext_vector_type(2)));

// 512 blocks x 512 thr (8 waves), 2 blocks/CU. o = blk&15, grp = blk>>4 (32).
// Wave w: 8 tiles of 16 batch rows, tile0 = grp*64 + w*8.
__global__ __launch_bounds__(512, 2) void mlp_fused(
    const float* __restrict__ x, const float* __restrict__ W1,
    const float* __restrict__ b1, const float* __restrict__ W2,
    const float* __restrict__ b2, float* __restrict__ out) {
    __shared__ f16x4 sm_a1[2048];     // [ct][lane] W1 frags      16 KiB
    __shared__ f32x4 sm_w2c[128];     // [ct][kg] 0.4*W2           2 KiB
    __shared__ f32x4 sm_b1c[128];     // [ct][kg] b1               2 KiB
    __shared__ float red[512];
    __shared__ float v_sm[16];
    __shared__ float c_sm;

    const int tid = threadIdx.x;
    const int o   = blockIdx.x & 15;
    const int grp = blockIdx.x >> 4;
    const float* W1o = W1 + (size_t)o * H_DIM * 16;
    const float* W2o = W2 + (size_t)o * H_DIM;
    const float* b1o = b1 + (size_t)o * H_DIM;

    // ---- phase A: stage fragments ----
#pragma unroll
    for (int i = 0; i < 4; ++i) {
        const int e = tid + 512 * i;          // 0..2047 = [ct][lane]
        const int l = e & 63, ct = e >> 6;
        const int row = l & 15, kg = l >> 4;
        const f32x4 wv = *reinterpret_cast<const f32x4*>(
            W1o + (size_t)(ct * 16 + row) * 16 + kg * 4);
        h16x2 q0 = __builtin_amdgcn_cvt_pkrtz(wv[0], wv[1]);
        h16x2 q1 = __builtin_amdgcn_cvt_pkrtz(wv[2], wv[3]);
        i32x2 vi; vi[0] = __builtin_bit_cast(int, q0); vi[1] = __builtin_bit_cast(int, q1);
        sm_a1[e] = __builtin_bit_cast(f16x4, vi);
    }
    if (tid < 128) {                          // [ct][kg]
        const int kg = tid & 3, ct = tid >> 2;
        f32x4 wv, bv;
#pragma unroll
        for (int r = 0; r < 4; ++r) {
            wv[r] = 0.4f * W2o[ct * 16 + kg * 4 + r];
            bv[r] = b1o[ct * 16 + kg * 4 + r];
        }
        sm_w2c[tid] = wv;
        sm_b1c[tid] = bv;
    }
    {   // v[i] = 0.6 sum_h W2[h] W1[h,i]
        const int i = tid & 15, hc = tid >> 4;     // 32 chunks x 16 h
        float a = 0.f;
#pragma unroll
        for (int hh = 0; hh < 16; ++hh) {
            const int h = hc * 16 + hh;
            a = fmaf(W2o[h], W1o[(size_t)h * 16 + i], a);
        }
        red[tid] = a;
    }
    __syncthreads();
    if (tid < 16) {
        float s = 0.f;
#pragma unroll
        for (int k = 0; k < 32; ++k) s += red[tid + 16 * k];
        v_sm[tid] = 0.6f * s;
    }
    const float cp = W2o[tid] * b1o[tid];
    __syncthreads();
    red[tid] = cp;
    __syncthreads();
    if (tid < 64) {
        float s = 0.f;
#pragma unroll
        for (int k = 0; k < 8; ++k) s += red[tid + 64 * k];
#pragma unroll
        for (int m = 1; m <= 32; m <<= 1) s += __shfl_xor(s, m, 64);
        if (tid == 0) c_sm = 0.6f * s + b2[o];
    }
    __syncthreads();

    // ---- phase B ----
    const int lane = tid & 63, w = tid >> 6;
    const int col = lane & 15, kg = lane >> 4;
    const int tile0 = grp * 64 + w * 8;

    const f32x4 vr = *reinterpret_cast<const f32x4*>(&v_sm[kg * 4]);
    const float c0 = c_sm;

    // x load + exact-f32 linear init + f16 fold
    f16x4 xf[8];
    float nl[8];
#pragma unroll
    for (int j = 0; j < 8; ++j) {
        const f32x4 xv = *reinterpret_cast<const f32x4*>(
            x + (size_t)((tile0 + j) * 16 + col) * 16 + kg * 4);
        float lp = xv[0] * vr[0];
        lp = fmaf(xv[1], vr[1], lp);
        lp = fmaf(xv[2], vr[2], lp);
        lp = fmaf(xv[3], vr[3], lp);
        nl[j] = lp;
        h16x2 q0 = __builtin_amdgcn_cvt_pkrtz(xv[0], xv[1]);
        h16x2 q1 = __builtin_amdgcn_cvt_pkrtz(xv[2], xv[3]);
        i32x2 xi; xi[0] = __builtin_bit_cast(int, q0); xi[1] = __builtin_bit_cast(int, q1);
        xf[j] = __builtin_bit_cast(f16x4, xi);
    }

#pragma unroll 2
    for (int ct = 0; ct < 32; ++ct) {
        const f16x4 A1 = sm_a1[ct * 64 + lane];   // ds_read_b64 (runtime idx OK)
        const f32x4 wv = sm_w2c[ct * 4 + kg];     // broadcast (kg-only addr)
        const f32x4 bv = sm_b1c[ct * 4 + kg];
#pragma unroll
        for (int j = 0; j < 8; ++j) {
            // stage1: d[r] = h[ct*16 + kg*4 + r] for b=col (bias via C)
            const f32x4 d = __builtin_amdgcn_mfma_f32_16x16x16f16(A1, xf[j], bv, 0, 0, 0);
            // stage2: 4 FMAs, |d| is a free VOP3 source modifier
            nl[j] = fmaf(wv[0], fabsf(d[0]), nl[j]);
            nl[j] = fmaf(wv[1], fabsf(d[1]), nl[j]);
            nl[j] = fmaf(wv[2], fabsf(d[2]), nl[j]);
            nl[j] = fmaf(wv[3], fabsf(d[3]), nl[j]);
        }
    }

    // reduce over kg (lanes differing in bits 4-5) and store
#pragma unroll
    for (int j = 0; j < 8; ++j) {
        float s = nl[j];
        s += __shfl_xor(s, 16, 64);
        s += __shfl_xor(s, 32, 64);
        if (lane < 16)
            out[(size_t)((tile0 + j) * 16 + lane) * 16 + o] = s + c0;
    }
}

extern "C" void kernel_launch(void* const* d_in, const int* in_sizes, int n_in,
                              void* d_out, int out_size, void* d_ws, size_t ws_size,
                              hipStream_t stream) {
    const float* x  = (const float*)d_in[0];
    const float* W1 = (const float*)d_in[1];
    const float* b1 = (const float*)d_in[2];
    const float* W2 = (const float*)d_in[3];
    const float* b2 = (const float*)d_in[4];
    float* out = (float*)d_out;

    mlp_fused<<<512, 512, 0, stream>>>(x, W1, b1, W2, b2, out);
}